// Round 2
// baseline (354.122 us; speedup 1.0000x reference)
//
#include <hip/hip_runtime.h>
#include <hip/hip_bf16.h>
#include <math.h>

// Problem constants: N=100000, K=10, T=7, D=7, O=32
#define T_ 7
#define D_ 7
#define K_ 10
#define O_ 32
#define NPB 256           // nodes per block (== blockDim.x)
#define NEG_SLOPE 0.01f

// ---------------- K0: zero the 32-float output accumulator (ws is poisoned)
__global__ void k0_zero(float* __restrict__ acc) {
    if (threadIdx.x < O_) acc[threadIdx.x] = 0.f;
}

// ---------------- fused: content einsum + masked mean + self emb + final GEMM
// + sigmoid + mean-reduce. One block = 256 nodes; t-loop stages xhet tile in
// LDS via coalesced float4 loads (fixes the 280B-stride uncoalesced pattern),
// h[56] lives in registers (kills the 45 MB het round-trip).
__global__ __launch_bounds__(256, 2) void k_fused(
    const float* __restrict__ xhet,   // [T,N,K,D]
    const float* __restrict__ xnode,  // [N,D]
    const int*   __restrict__ types,  // [N]
    const float* __restrict__ Wc,     // [T,D,D]
    const float* __restrict__ bc,     // [T,D]
    const float* __restrict__ Wagg,   // [O,56]
    const float* __restrict__ bagg,   // [O]
    float* __restrict__ acc_out,      // [O] global accumulator
    int N)
{
    __shared__ __align__(16) float tile[NPB * 70];   // 71680 B
    __shared__ float4 sW[O_ * 14];                   // 7168 B
    __shared__ float  sb[O_];
    __shared__ float  sacc[O_];
    // total 79104 B -> 2 blocks/CU (160 KiB LDS)

    const int tx = threadIdx.x;
    const int nodeBase = blockIdx.x * NPB;
    const int n = nodeBase + tx;
    const bool active = (n < N);
    const int valid = min(NPB, N - nodeBase);
    const int L = valid * 70;                        // floats in this block's tile

    // stage W_agg (flat: 32*56 = 1792 floats = 448 float4, base 16B-aligned)
    for (int i = tx; i < O_ * 14; i += NPB) sW[i] = ((const float4*)Wagg)[i];
    if (tx < O_) { sb[tx] = bagg[tx]; sacc[tx] = 0.f; }
    // visibility of sW/sb/sacc is covered by the first __syncthreads below

    // per-thread self inputs (tiny: 2.8 MB total, L2 absorbs)
    float x[D_]; int tp = -1;
    if (active) {
        tp = types[n];
        #pragma unroll
        for (int d = 0; d < D_; ++d) x[d] = xnode[(size_t)n * D_ + d];
    } else {
        #pragma unroll
        for (int d = 0; d < D_; ++d) x[d] = 0.f;
    }

    float h[(T_ + 1) * D_];                          // concat layout: h[t*7+o], self at 49..55
    #pragma unroll
    for (int j = 0; j < (T_ + 1) * D_; ++j) h[j] = 0.f;

    for (int t = 0; t < T_; ++t) {
        // block-uniform weights -> scalar registers
        float w[D_][D_], bias[D_];
        #pragma unroll
        for (int o = 0; o < D_; ++o) {
            bias[o] = bc[t * D_ + o];
            #pragma unroll
            for (int d = 0; d < D_; ++d) w[o][d] = Wc[(t * D_ + o) * D_ + d];
        }

        __syncthreads();   // previous iteration's readers done before overwrite
        const float* src = xhet + ((size_t)t * N + nodeBase) * 70;  // 16B-aligned (nodeBase%256==0)
        const int L4 = L >> 2;
        for (int i = tx; i < L4; i += NPB)
            ((float4*)tile)[i] = ((const float4*)src)[i];          // coalesced 16B/lane
        for (int i = (L4 << 2) + tx; i < L; i += NPB)
            tile[i] = src[i];                                      // generic tail
        __syncthreads();

        if (active) {
            const float* myp = tile + tx * 70;
            float acc[D_] = {0.f, 0.f, 0.f, 0.f, 0.f, 0.f, 0.f};
            float cnt = 0.f;
            #pragma unroll
            for (int kk = 0; kk < K_ / 2; ++kk) {   // k in pairs: 14 floats = 7 aligned float2
                float f[14];
                const float2* p2 = (const float2*)(myp + kk * 14);
                #pragma unroll
                for (int j = 0; j < 7; ++j) { float2 v = p2[j]; f[2*j] = v.x; f[2*j+1] = v.y; }
                #pragma unroll
                for (int hh = 0; hh < 2; ++hh) {
                    float pre[D_];
                    #pragma unroll
                    for (int o = 0; o < D_; ++o) pre[o] = bias[o];
                    #pragma unroll
                    for (int d = 0; d < D_; ++d) {
                        const float xv = f[hh * 7 + d];
                        #pragma unroll
                        for (int o = 0; o < D_; ++o) pre[o] = fmaf(xv, w[o][d], pre[o]);
                    }
                    bool nz = false;
                    #pragma unroll
                    for (int o = 0; o < D_; ++o) nz = nz || (pre[o] != 0.f);
                    cnt += nz ? 1.f : 0.f;
                    #pragma unroll
                    for (int o = 0; o < D_; ++o)
                        acc[o] += (pre[o] >= 0.f) ? pre[o] : NEG_SLOPE * pre[o];
                }
            }
            const float inv = 1.f / fmaxf(cnt, 1.f);
            #pragma unroll
            for (int o = 0; o < D_; ++o) h[t * D_ + o] = acc[o] * inv;

            // self candidate with this t's (uniform) weights; select on type match.
            // replaces a per-lane gather of W_content[types[n]] with +49 FMA/t.
            float ps[D_];
            #pragma unroll
            for (int o = 0; o < D_; ++o) {
                float p = bias[o];
                #pragma unroll
                for (int d = 0; d < D_; ++d) p = fmaf(x[d], w[o][d], p);
                ps[o] = (p >= 0.f) ? p : NEG_SLOPE * p;
            }
            if (tp == t) {
                #pragma unroll
                for (int o = 0; o < D_; ++o) h[T_ * D_ + o] = ps[o];
            }
        }
    }

    // ---- epilogue: [56] x [O,56]^T + bias -> sigmoid -> reduce
    const int lane = tx & 63;
    #pragma unroll 4
    for (int o = 0; o < O_; ++o) {
        float s = sb[o];
        #pragma unroll
        for (int q = 0; q < 14; ++q) {
            float4 wv = sW[o * 14 + q];
            s += h[4*q] * wv.x + h[4*q+1] * wv.y + h[4*q+2] * wv.z + h[4*q+3] * wv.w;
        }
        float val = active ? 1.f / (1.f + __expf(-s)) : 0.f;
        #pragma unroll
        for (int off = 32; off >= 1; off >>= 1) val += __shfl_down(val, off);
        if (lane == 0) atomicAdd(&sacc[o], val);
    }
    __syncthreads();
    if (tx < O_) atomicAdd(acc_out + tx, sacc[tx]);
}

// ---------------- K3: divide by N into d_out
__global__ void k3_finish(const float* __restrict__ acc, float* __restrict__ out, float invN) {
    if (threadIdx.x < O_) out[threadIdx.x] = acc[threadIdx.x] * invN;
}

extern "C" void kernel_launch(void* const* d_in, const int* in_sizes, int n_in,
                              void* d_out, int out_size, void* d_ws, size_t ws_size,
                              hipStream_t stream) {
    const float* xnode = (const float*)d_in[0];   // [N,D]
    const float* xhet  = (const float*)d_in[1];   // [T,N,K,D]
    const int*   types = (const int*)d_in[2];     // [N]
    const float* Wc    = (const float*)d_in[3];   // [T,D,D]
    const float* bc    = (const float*)d_in[4];   // [T,D]
    const float* Wagg  = (const float*)d_in[5];   // [O,56]
    const float* bagg  = (const float*)d_in[6];   // [O]
    float* out = (float*)d_out;

    const int N = in_sizes[2];
    float* acc_out = (float*)d_ws;                // 32 floats

    const int nblk = (N + NPB - 1) / NPB;

    k0_zero<<<1, 64, 0, stream>>>(acc_out);
    k_fused<<<nblk, NPB, 0, stream>>>(xhet, xnode, types, Wc, bc, Wagg, bagg, acc_out, N);
    k3_finish<<<1, 64, 0, stream>>>(acc_out, out, 1.f / (float)N);
}